// Round 2
// baseline (35.069 us; speedup 1.0000x reference)
//
#include <hip/hip_runtime.h>
#include <math.h>

#define NP 256      // ids_per_batch
#define NK 16       // imgs_per_id
#define ND 2048     // feature_dim
#define MARGIN 10.0f
#define EPSV 1e-12f

typedef short bf16x8 __attribute__((ext_vector_type(8)));   // 8 bf16 (4 VGPRs)
typedef float f32x4 __attribute__((ext_vector_type(4)));    // MFMA C/D

static __device__ __forceinline__ unsigned short f2bf(float f) {
  unsigned u = __float_as_uint(f);
  unsigned r = (u + 0x7fffu + ((u >> 16) & 1u)) >> 16;  // RNE
  return (unsigned short)r;
}

// ---------------------------------------------------------------------------
// A: per-class center (bf16 out), cc = ||c||^2, intra_max, init inter=+inf.
// One block per class p; 512 threads, each owns one float4 column.
// ---------------------------------------------------------------------------
__global__ __launch_bounds__(512) void k_center_intra(
    const float* __restrict__ F, unsigned short* __restrict__ Cb,
    float* __restrict__ cc, float* __restrict__ out) {
  const int p = blockIdx.x;
  const int t = threadIdx.x;
  const int d = t * 4;

  float4 x[NK];
#pragma unroll
  for (int k = 0; k < NK; ++k)
    x[k] = *reinterpret_cast<const float4*>(&F[((size_t)(p * NK + k)) * ND + d]);

  float4 c;
  c.x = c.y = c.z = c.w = 0.f;
#pragma unroll
  for (int k = 0; k < NK; ++k) {
    c.x += x[k].x; c.y += x[k].y; c.z += x[k].z; c.w += x[k].w;
  }
  const float inv = 1.0f / 16.0f;
  c.x *= inv; c.y *= inv; c.z *= inv; c.w *= inv;

  // bf16 center store (8 B/thread, fully coalesced)
  ushort4 cb;
  cb.x = f2bf(c.x); cb.y = f2bf(c.y); cb.z = f2bf(c.z); cb.w = f2bf(c.w);
  *reinterpret_cast<ushort4*>(&Cb[(size_t)p * ND + d]) = cb;

  float ccp = c.x * c.x + c.y * c.y + c.z * c.z + c.w * c.w;

  float acc[NK];
#pragma unroll
  for (int k = 0; k < NK; ++k) {
    float dx = x[k].x - c.x, dy = x[k].y - c.y;
    float dz = x[k].z - c.z, dw = x[k].w - c.w;
    acc[k] = dx * dx + dy * dy + dz * dz + dw * dw;
  }

  // wave butterfly reduce (17 values)
#pragma unroll
  for (int k = 0; k < NK; ++k) {
    float v = acc[k];
#pragma unroll
    for (int m = 32; m > 0; m >>= 1) v += __shfl_xor(v, m);
    acc[k] = v;
  }
  {
    float v = ccp;
#pragma unroll
    for (int m = 32; m > 0; m >>= 1) v += __shfl_xor(v, m);
    ccp = v;
  }

  __shared__ float red[8][NK + 1];
  const int wave = t >> 6, lane = t & 63;
  if (lane == 0) {
#pragma unroll
    for (int k = 0; k < NK; ++k) red[wave][k] = acc[k];
    red[wave][NK] = ccp;
  }
  __syncthreads();
  if (t == 0) {
    float m = 0.f;
#pragma unroll
    for (int k = 0; k < NK; ++k) {
      float s = 0.f;
#pragma unroll
      for (int w = 0; w < 8; ++w) s += red[w][k];
      m = fmaxf(m, sqrtf(fmaxf(s, EPSV)));
    }
    out[1 + p] = m;  // intra_max
    float s = 0.f;
#pragma unroll
    for (int w = 0; w < 8; ++w) s += red[w][NK];
    cc[p] = s;
    out[1 + NP + p] = INFINITY;  // init for atomicMin in kernel B
  }
}

// ---------------------------------------------------------------------------
// B: G-tile = C * C^T via MFMA bf16; fused inter_min epilogue (atomicMin on
// positive-float int bits). Grid (16,4): block = 16 p-rows x 64 q-cols,
// 4 waves, each wave one 16x16 tile over full K=2048.
// ---------------------------------------------------------------------------
__global__ __launch_bounds__(256) void k_gemm_inter(
    const unsigned short* __restrict__ Cb, const float* __restrict__ cc,
    float* __restrict__ out) {
  const int t = threadIdx.x;
  const int wave = t >> 6, lane = t & 63;
  const int p0 = blockIdx.x * 16;
  const int q0 = blockIdx.y * 64 + wave * 16;
  const int lr = lane & 15;        // A row / B col within tile
  const int kg = (lane >> 4) * 8;  // k-base within 32-chunk

  const unsigned short* ap = &Cb[(size_t)(p0 + lr) * ND + kg];
  const unsigned short* bp = &Cb[(size_t)(q0 + lr) * ND + kg];

  f32x4 acc = {0.f, 0.f, 0.f, 0.f};
#pragma unroll 8
  for (int k0 = 0; k0 < ND; k0 += 32) {
    bf16x8 a = *reinterpret_cast<const bf16x8*>(ap + k0);
    bf16x8 b = *reinterpret_cast<const bf16x8*>(bp + k0);
    acc = __builtin_amdgcn_mfma_f32_16x16x32_bf16(a, b, acc, 0, 0, 0);
  }

  // C/D layout: col = lane&15, row = (lane>>4)*4 + reg
  const int rbase = (lane >> 4) * 4;
  const int qg = q0 + lr;
  const float ccq = cc[qg];
  float cdm[4];
#pragma unroll
  for (int r = 0; r < 4; ++r) {
    const int pg = p0 + rbase + r;
    const float cd2 = cc[pg] + ccq - 2.0f * acc[r];
    cdm[r] = (pg == qg) ? INFINITY : sqrtf(fmaxf(cd2, EPSV));
  }
  // min across the 16 lanes of this row-group (xor bits 0..3 stay in group)
#pragma unroll
  for (int r = 0; r < 4; ++r) {
#pragma unroll
    for (int m = 8; m > 0; m >>= 1) cdm[r] = fminf(cdm[r], __shfl_xor(cdm[r], m));
  }
  if (lr == 0) {
#pragma unroll
    for (int r = 0; r < 4; ++r) {
      const int pg = p0 + rbase + r;
      atomicMin(reinterpret_cast<int*>(out) + 1 + NP + pg,
                __float_as_int(cdm[r]));
    }
  }
}

// ---------------------------------------------------------------------------
// C: loss = mean(relu(intra_max - inter_min + MARGIN)); single block.
// ---------------------------------------------------------------------------
__global__ __launch_bounds__(256) void k_loss(float* __restrict__ out) {
  const int t = threadIdx.x;
  const float im = out[1 + t];
  const float in_ = out[1 + NP + t];
  float v = fmaxf(im - in_ + MARGIN, 0.f);
#pragma unroll
  for (int m = 32; m > 0; m >>= 1) v += __shfl_xor(v, m);
  __shared__ float red[4];
  if ((t & 63) == 0) red[t >> 6] = v;
  __syncthreads();
  if (t == 0) out[0] = (red[0] + red[1] + red[2] + red[3]) / (float)NP;
}

// ---------------------------------------------------------------------------
extern "C" void kernel_launch(void* const* d_in, const int* in_sizes, int n_in,
                              void* d_out, int out_size, void* d_ws,
                              size_t ws_size, hipStream_t stream) {
  const float* F = (const float*)d_in[0];  // features [4096, 2048] fp32
  float* out = (float*)d_out;              // [513]: loss, intra_max, inter_min

  unsigned short* Cb = (unsigned short*)d_ws;       // 256*2048 bf16 (1 MB)
  float* cc = (float*)(Cb + (size_t)NP * ND);       // 256 fp32

  k_center_intra<<<NP, 512, 0, stream>>>(F, Cb, cc, out);
  k_gemm_inter<<<dim3(16, 4), 256, 0, stream>>>(Cb, cc, out);
  k_loss<<<1, 256, 0, stream>>>(out);
}